// Round 1
// baseline (427.257 us; speedup 1.0000x reference)
//
#include <hip/hip_runtime.h>
#include <math.h>

#define DD 160
#define HH 160
#define WW 160
#define BB 4
#define K 11
#define RAD 5
#define TH 16
#define TW 16
#define DCH 40                    // output planes per block along D
#define NPLANES (DCH + 2 * RAD)   // 50 input planes iterated
#define HALO_H (TH + 2 * RAD)     // 26
#define HALO_W (TW + 2 * RAD)     // 26
#define NDCH (DD / DCH)           // 4

struct GaussW { float g[K]; };

__global__ __launch_bounds__(256)
void ssim3d_fused_kernel(const float* __restrict__ img1,
                         const float* __restrict__ img2,
                         float* __restrict__ out,
                         GaussW gw)
{
    __shared__ float s1[HALO_H * HALO_W];
    __shared__ float s2[HALO_H * HALO_W];
    __shared__ float tmp[5 * HALO_H * TW];   // [stat][r 0..25][c 0..15]
    __shared__ float wsum[4];

    const int tid = threadIdx.x;
    const int tx = tid & 15;
    const int ty = tid >> 4;

    const int blk = blockIdx.x;
    const int bw = blk % 10;
    const int bh = (blk / 10) % 10;
    const int bd = (blk / 100) % NDCH;
    const int bb = blk / (100 * NDCH);

    const int oh0 = bh * TH;
    const int ow0 = bw * TW;
    const int od0 = bd * DCH;

    const float* base1 = img1 + (size_t)bb * DD * HH * WW;
    const float* base2 = img2 + (size_t)bb * DD * HH * WW;

    float g[K];
#pragma unroll
    for (int i = 0; i < K; ++i) g[i] = gw.g[i];

    // D-direction scatter accumulators: a*[i] <-> output plane od = d - RAD + i
    float a1[K], a2[K], a11[K], a22[K], a12[K];
#pragma unroll
    for (int i = 0; i < K; ++i) { a1[i]=0.f; a2[i]=0.f; a11[i]=0.f; a22[i]=0.f; a12[i]=0.f; }

    float local_sum = 0.f;

    for (int p = 0; p < NPLANES; ++p) {
        const int d = od0 - RAD + p;
        const bool dval = (d >= 0) && (d < DD);

        // ---- stage A: load 26x26 halo tiles of this plane (zero-pad OOB) ----
        for (int e = tid; e < HALO_H * HALO_W; e += 256) {
            int r = e / HALO_W;
            int c = e - r * HALO_W;
            int ih = oh0 - RAD + r;
            int iw = ow0 - RAD + c;
            float v1 = 0.f, v2 = 0.f;
            if (dval && (unsigned)ih < (unsigned)HH && (unsigned)iw < (unsigned)WW) {
                size_t idx = ((size_t)d * HH + ih) * WW + iw;
                v1 = base1[idx];
                v2 = base2[idx];
            }
            s1[e] = v1;
            s2[e] = v2;
        }
        __syncthreads();

        // ---- stage B: W-convolution of the 5 stats into tmp ----
        for (int e = tid; e < HALO_H * TW; e += 256) {
            int r = e >> 4;
            int c = e & 15;
            float t1 = 0.f, t2 = 0.f, t11 = 0.f, t22 = 0.f, t12 = 0.f;
#pragma unroll
            for (int k = 0; k < K; ++k) {
                float wgt = g[k];
                float av = s1[r * HALO_W + c + k];
                float bv = s2[r * HALO_W + c + k];
                t1  += wgt * av;
                t2  += wgt * bv;
                t11 += wgt * av * av;
                t22 += wgt * bv * bv;
                t12 += wgt * av * bv;
            }
            tmp[0 * (HALO_H * TW) + e] = t1;
            tmp[1 * (HALO_H * TW) + e] = t2;
            tmp[2 * (HALO_H * TW) + e] = t11;
            tmp[3 * (HALO_H * TW) + e] = t22;
            tmp[4 * (HALO_H * TW) + e] = t12;
        }
        __syncthreads();

        // ---- stage C: H-convolution -> P, D scatter-accumulate, emit ----
        float P1 = 0.f, P2 = 0.f, P11 = 0.f, P22 = 0.f, P12 = 0.f;
#pragma unroll
        for (int k = 0; k < K; ++k) {
            float wgt = g[k];
            int off = (ty + k) * TW + tx;
            P1  += wgt * tmp[0 * (HALO_H * TW) + off];
            P2  += wgt * tmp[1 * (HALO_H * TW) + off];
            P11 += wgt * tmp[2 * (HALO_H * TW) + off];
            P22 += wgt * tmp[3 * (HALO_H * TW) + off];
            P12 += wgt * tmp[4 * (HALO_H * TW) + off];
        }
#pragma unroll
        for (int i = 0; i < K; ++i) {
            float wgt = g[K - 1 - i];   // weight for output plane d - RAD + i
            a1[i]  += wgt * P1;
            a2[i]  += wgt * P2;
            a11[i] += wgt * P11;
            a22[i] += wgt * P22;
            a12[i] += wgt * P12;
        }
        if (p >= 2 * RAD) {
            // output plane od = d - RAD is complete in slot 0
            float mu1 = a1[0], mu2 = a2[0];
            float e11 = a11[0], e22 = a22[0], e12 = a12[0];
            float mu1s = mu1 * mu1;
            float mu2s = mu2 * mu2;
            float mu12 = mu1 * mu2;
            float sg1 = e11 - mu1s;
            float sg2 = e22 - mu2s;
            float sg12 = e12 - mu12;
            const float C1c = 0.0001f;   // 0.01^2
            const float C2c = 0.0009f;   // 0.03^2
            float num = (2.f * mu12 + C1c) * (2.f * sg12 + C2c);
            float den = (mu1s + mu2s + C1c) * (sg1 + sg2 + C2c);
            local_sum += num / den;
        }
        // shift accumulators down by one plane
#pragma unroll
        for (int i = 0; i < K - 1; ++i) {
            a1[i]  = a1[i + 1];
            a2[i]  = a2[i + 1];
            a11[i] = a11[i + 1];
            a22[i] = a22[i + 1];
            a12[i] = a12[i + 1];
        }
        a1[K-1] = 0.f; a2[K-1] = 0.f; a11[K-1] = 0.f; a22[K-1] = 0.f; a12[K-1] = 0.f;
    }

    // ---- block reduction -> one atomic per block ----
    float v = local_sum;
#pragma unroll
    for (int off = 32; off > 0; off >>= 1)
        v += __shfl_down(v, off, 64);
    if ((tid & 63) == 0) wsum[tid >> 6] = v;
    __syncthreads();
    if (tid == 0) {
        float bsum = wsum[0] + wsum[1] + wsum[2] + wsum[3];
        const float inv_n = 1.0f / ((float)BB * DD * HH * WW);
        atomicAdd(out, bsum * inv_n);
    }
}

extern "C" void kernel_launch(void* const* d_in, const int* in_sizes, int n_in,
                              void* d_out, int out_size, void* d_ws, size_t ws_size,
                              hipStream_t stream) {
    const float* img1 = (const float*)d_in[0];
    const float* img2 = (const float*)d_in[1];
    // d_in[2] (the 11^3 window) is separable g(x)g(y)g(z); rebuild g host-side
    // in double to match numpy's float64 construction, then cast.
    float* out = (float*)d_out;

    GaussW gw;
    double gd[K], sum = 0.0;
    for (int i = 0; i < K; ++i) {
        double x = (double)(i - K / 2);
        gd[i] = exp(-(x * x) / (2.0 * 1.5 * 1.5));
        sum += gd[i];
    }
    for (int i = 0; i < K; ++i) gw.g[i] = (float)(gd[i] / sum);

    // d_out is re-poisoned to 0xAA before every timed launch; zero it.
    hipMemsetAsync(d_out, 0, sizeof(float), stream);

    dim3 grid(BB * NDCH * 10 * 10);   // 1600 blocks
    dim3 block(256);
    hipLaunchKernelGGL(ssim3d_fused_kernel, grid, block, 0, stream,
                       img1, img2, out, gw);
}